// Round 1
// baseline (81.662 us; speedup 1.0000x reference)
//
#include <hip/hip_runtime.h>
#include <math.h>

#ifndef M_PI
#define M_PI 3.14159265358979323846
#endif

#define NPTS 8192
#define KCOMP 64
#define NBIN 150          // bins of width 0.08 over [-6, 6]
#define XMIN -6.0f
#define BINW_INV 12.5f    // 1/0.08
// kern = exp(-8192 d^2): underflows to 0.0f for d > 0.112; at d=0.08 it is
// 1.8e-23 (< 1 ulp of the per-point sum). Bin windowing at +-1 bin omits only
// pairs with d > 0.08 -> numerically exact vs the f32 reference.

// Single-instruction hardware exp2 (v_exp_f32).
__device__ __forceinline__ float fexp2(float a) {
#if __has_builtin(__builtin_amdgcn_exp2f)
  return __builtin_amdgcn_exp2f(a);
#else
  float r;
  asm("v_exp_f32 %0, %1" : "=v"(r) : "v"(a));
  return r;
#endif
}

// ws layout (floats):
//   [0,     8192)  xs_s : bin-sorted x, pre-scaled by s = sqrt(8192*log2e)
//   [8192, 16384)  xs_u : bin-sorted x, unscaled
//   [16384,16544)  bst  : (int) 151 bin-start offsets (padded to 160)
//   [16544,16608)  sa   : mixture amplitude  w_k * rsqrt(2*pi*var_k)
//   [16608,16672)  sq   : 0.5*log2(e)/var_k
//   [16672,16736)  smn  : means

// --- K1: counting-sort into bins + softmax/component precompute (1 block) ---
__global__ __launch_bounds__(1024) void bin_kernel(
    const float* __restrict__ x,
    const float* __restrict__ logits,
    const float* __restrict__ means,
    const float* __restrict__ log_vars,
    float* __restrict__ ws,
    float* __restrict__ out) {
  __shared__ int hist[NBIN];
  __shared__ int sc[NBIN];
  __shared__ int ofs[NBIN];
  const int t = threadIdx.x;
  const float s = sqrtf(8192.0f * 1.44269504088896340736f);

  float xv[8];
  int bn[8];
#pragma unroll
  for (int r = 0; r < 8; ++r) xv[r] = x[t + r * 1024];
  if (t < NBIN) hist[t] = 0;
  __syncthreads();
#pragma unroll
  for (int r = 0; r < 8; ++r) {
    int b = (int)((xv[r] - XMIN) * BINW_INV);
    b = b < 0 ? 0 : (b > NBIN - 1 ? NBIN - 1 : b);
    bn[r] = b;
    atomicAdd(&hist[b], 1);
  }
  __syncthreads();
  // Hillis-Steele inclusive scan over 150 bins (8 steps)
  if (t < NBIN) sc[t] = hist[t];
  __syncthreads();
  for (int off = 1; off < NBIN; off <<= 1) {
    int v = 0;
    if (t < NBIN) v = sc[t] + ((t >= off) ? sc[t - off] : 0);
    __syncthreads();
    if (t < NBIN) sc[t] = v;
    __syncthreads();
  }
  float* xs_s = ws;
  float* xs_u = ws + 8192;
  int* bst = (int*)(ws + 16384);
  if (t < NBIN) {
    int st = sc[t] - hist[t];   // exclusive start
    ofs[t] = st;
    bst[t] = st;
  }
  if (t == 0) { bst[NBIN] = NPTS; out[0] = 0.0f; }
  __syncthreads();
#pragma unroll
  for (int r = 0; r < 8; ++r) {
    int pos = atomicAdd(&ofs[bn[r]], 1);
    xs_u[pos] = xv[r];
    xs_s[pos] = xv[r] * s;
  }
  // wave 0: softmax over K=64 logits + component params
  if (t < KCOMP) {
    float l = logits[t];
    float m = l;
#pragma unroll
    for (int off = 32; off > 0; off >>= 1) m = fmaxf(m, __shfl_xor(m, off));
    float e = expf(l - m);
    float ssum = e;
#pragma unroll
    for (int off = 32; off > 0; off >>= 1) ssum += __shfl_xor(ssum, off);
    float w = e / ssum;
    float var = expf(log_vars[t]);
    float* sa = ws + 16384 + 160;
    float* sq = sa + 64;
    float* smn = sq + 64;
    sa[t] = w * rsqrtf(2.0f * (float)M_PI * var);
    sq[t] = 0.72134752044448170368f / var;   // 0.5*log2(e)/var
    smn[t] = means[t];
  }
}

// --- K2: windowed KDE + mixture pdf + MSE reduction ------------------------
// 256 blocks x 256 threads = 1024 waves; wave gw owns points {gw + 1024*r},
// r=0..7 (stride-interleaved -> every wave mixes dense-center & sparse-tail
// points, balancing the variable neighbor counts).
__global__ __launch_bounds__(256) void kde_final_kernel(
    const float* __restrict__ ws,
    float* __restrict__ out) {
  const float inv_norm = 1.0f / (2.50662827463100050242f * 64.0f);
  const int t = threadIdx.x;
  const int lane = t & 63;
  const int gw = blockIdx.x * 4 + (t >> 6);
  const float* xs_s = ws;
  const float* xs_u = ws + 8192;
  const int* bst = (const int*)(ws + 16384);
  const float* sa = ws + 16384 + 160;
  const float* sq = sa + 64;
  const float* smn = sq + 64;
  // lane k owns mixture component k (K = wave size = 64)
  const float sal = sa[lane], sql = sq[lane], sml = smn[lane];

  float vsum = 0.0f;
#pragma unroll
  for (int r = 0; r < 8; ++r) {
    const int p = gw + r * 1024;
    const float u = xs_u[p];    // broadcast load
    const float us = xs_s[p];
    int b = (int)((u - XMIN) * BINW_INV);
    b = b < 0 ? 0 : (b > NBIN - 1 ? NBIN - 1 : b);
    const int j0 = bst[b > 0 ? b - 1 : 0];
    const int j1 = bst[(b + 2) > NBIN ? NBIN : (b + 2)];
    // windowed KDE: lanes split the neighbor list
    float acc = 0.0f;
    for (int j = j0 + lane; j < j1; j += 64) {
      float d = us - xs_s[j];
      acc += fexp2(-(d * d));
    }
    // mixture: one component per lane
    float dm = u - sml;
    float mixl = sal * fexp2(-(sql * dm) * dm);
    // joint butterfly reduce (all lanes end with the wave sums)
#pragma unroll
    for (int off = 32; off > 0; off >>= 1) {
      acc += __shfl_xor(acc, off);
      mixl += __shfl_xor(mixl, off);
    }
    float diff = mixl - acc * inv_norm;
    vsum += diff * diff;
  }
  __shared__ float wsum[4];
  if (lane == 0) wsum[t >> 6] = vsum;
  __syncthreads();
  if (t == 0) atomicAdd(out, (wsum[0] + wsum[1]) + (wsum[2] + wsum[3]));
}

extern "C" void kernel_launch(void* const* d_in, const int* in_sizes, int n_in,
                              void* d_out, int out_size, void* d_ws, size_t ws_size,
                              hipStream_t stream) {
  const float* x     = (const float*)d_in[0];
  const float* wl    = (const float*)d_in[1];
  const float* means = (const float*)d_in[2];
  const float* lv    = (const float*)d_in[3];
  float* out = (float*)d_out;
  float* ws  = (float*)d_ws;

  bin_kernel<<<1, 1024, 0, stream>>>(x, wl, means, lv, ws, out);
  kde_final_kernel<<<256, 256, 0, stream>>>(ws, out);
}

// Round 3
// 68.613 us; speedup vs baseline: 1.1902x; 1.1902x over previous
//
#include <hip/hip_runtime.h>
#include <math.h>

#ifndef M_PI
#define M_PI 3.14159265358979323846
#endif

#define NPTS 8192
#define KCOMP 64
#define NBIN 150          // bins of width 0.08 over [-6, 6]
#define XMIN -6.0f
#define BINW_INV 12.5f    // 1/0.08
#define NBLK 256          // 1 block per CU
#define NTHR 1024         // 16 waves
// kern = exp(-8192 d^2): underflows to 0.0f for d > 0.112; at d=0.08 it is
// 1.8e-23 (< 1 ulp of the per-point sum). Bin windowing at +-1 bin omits only
// pairs with d > 0.08 -> numerically exact vs the f32 reference.
//
// Design (round-2 post-mortem): whole dataset = 32 KB -> every block
// redundantly counting-sorts x into its OWN LDS (no inter-block dependency,
// no serial sort kernel, no global scatter). Round-1 fused version used
// 66.5 KB static LDS (two copies of x) and only 64 blocks; this version keeps
// ONE unscaled copy (scaled value recovered with a single v_fma in the inner
// loop) -> 34 KB LDS, and 256 blocks so all CUs work.

// Single-instruction hardware exp2 (v_exp_f32).
__device__ __forceinline__ float fexp2(float a) {
#if __has_builtin(__builtin_amdgcn_exp2f)
  return __builtin_amdgcn_exp2f(a);
#else
  float r;
  asm("v_exp_f32 %0, %1" : "=v"(r) : "v"(a));
  return r;
#endif
}

__global__ __launch_bounds__(NTHR) void gmm_kernel(
    const float* __restrict__ x,
    const float* __restrict__ logits,
    const float* __restrict__ means,
    const float* __restrict__ log_vars,
    float* __restrict__ out) {
  __shared__ alignas(16) float xs[NPTS];   // bin-sorted, UNSCALED (32 KB)
  __shared__ int hist[NBIN];
  __shared__ int sc[NBIN];
  __shared__ int ofs[NBIN];
  __shared__ int bst[NBIN + 2];
  __shared__ float sa[KCOMP], sq[KCOMP], smn[KCOMP];
  __shared__ float wsum[16];

  const int t = threadIdx.x;
  const float s = sqrtf(8192.0f * 1.44269504088896340736f);  // sqrt(8192*log2e)

  // ---- phase 1: block-local counting sort of ALL 8192 points ----
  float xv[8];
  int bn[8];
#pragma unroll
  for (int r = 0; r < 8; ++r) xv[r] = x[t + r * NTHR];
  if (t < NBIN) hist[t] = 0;
  __syncthreads();
#pragma unroll
  for (int r = 0; r < 8; ++r) {
    int b = (int)((xv[r] - XMIN) * BINW_INV);
    b = b < 0 ? 0 : (b > NBIN - 1 ? NBIN - 1 : b);
    bn[r] = b;
    atomicAdd(&hist[b], 1);
  }
  // wave 0: softmax over K=64 logits + component params (independent of the
  // histogram -> overlaps the atomic settle before the barrier)
  if (t < KCOMP) {
    float l = logits[t];
    float m = l;
#pragma unroll
    for (int off = 32; off > 0; off >>= 1) m = fmaxf(m, __shfl_xor(m, off));
    float e = expf(l - m);
    float ssum = e;
#pragma unroll
    for (int off = 32; off > 0; off >>= 1) ssum += __shfl_xor(ssum, off);
    float w = e / ssum;
    float var = expf(log_vars[t]);
    sa[t] = w * rsqrtf(2.0f * (float)M_PI * var);   // amplitude
    sq[t] = 0.72134752044448170368f / var;          // 0.5*log2(e)/var
    smn[t] = means[t];
  }
  __syncthreads();
  // Hillis-Steele inclusive scan over 150 bins (8 steps)
  if (t < NBIN) sc[t] = hist[t];
  __syncthreads();
  for (int off = 1; off < NBIN; off <<= 1) {
    int v = 0;
    if (t < NBIN) v = sc[t] + ((t >= off) ? sc[t - off] : 0);
    __syncthreads();
    if (t < NBIN) sc[t] = v;
    __syncthreads();
  }
  if (t < NBIN) {
    int st = sc[t] - hist[t];   // exclusive start
    ofs[t] = st;
    bst[t] = st;
  }
  if (t == 0) bst[NBIN] = NPTS;
  __syncthreads();
#pragma unroll
  for (int r = 0; r < 8; ++r) {
    int pos = atomicAdd(&ofs[bn[r]], 1);
    xs[pos] = xv[r];
  }
  __syncthreads();

  // ---- phase 2: windowed KDE + mixture pdf + MSE, all from LDS ----
  const float inv_norm = 1.0f / (2.50662827463100050242f * 64.0f);
  const int lane = t & 63;
  const int wv = t >> 6;
  const int gw = blockIdx.x * 16 + wv;   // 4096 waves, 2 sorted positions each
  // lane k owns mixture component k (K = wave size = 64)
  const float sal = sa[lane], sql = sq[lane], sml = smn[lane];

  float vsum = 0.0f;
#pragma unroll
  for (int r = 0; r < 2; ++r) {
    const int p = gw + r * 4096;     // pair left-half/right-half quantiles
    const float u = xs[p];           // LDS broadcast
    const float us = u * s;
    int b = (int)((u - XMIN) * BINW_INV);
    b = b < 0 ? 0 : (b > NBIN - 1 ? NBIN - 1 : b);
    const int j0 = bst[b > 0 ? b - 1 : 0];
    const int j1 = bst[(b + 2) > NBIN ? NBIN : (b + 2)];
    // windowed KDE: lanes split the neighbor list (stride-1 -> 2 lanes/bank, free)
    float acc = 0.0f;
    for (int j = j0 + lane; j < j1; j += 64) {
      float d = fmaf(xs[j], -s, us);   // s*(u - xj), one v_fma
      acc += fexp2(-(d * d));
    }
    // mixture: one component per lane
    float dm = u - sml;
    float mixl = sal * fexp2(-(sql * dm) * dm);
    // joint butterfly reduce (all lanes end with the wave sums)
#pragma unroll
    for (int off = 32; off > 0; off >>= 1) {
      acc += __shfl_xor(acc, off);
      mixl += __shfl_xor(mixl, off);
    }
    float diff = mixl - acc * inv_norm;
    vsum += diff * diff;
  }
  if (lane == 0) wsum[wv] = vsum;
  __syncthreads();
  if (t < 16) {
    float v = wsum[t];
#pragma unroll
    for (int off = 8; off > 0; off >>= 1) v += __shfl_xor(v, off);
    if (t == 0) atomicAdd(out, v);
  }
}

extern "C" void kernel_launch(void* const* d_in, const int* in_sizes, int n_in,
                              void* d_out, int out_size, void* d_ws, size_t ws_size,
                              hipStream_t stream) {
  const float* x     = (const float*)d_in[0];
  const float* wl    = (const float*)d_in[1];
  const float* means = (const float*)d_in[2];
  const float* lv    = (const float*)d_in[3];
  float* out = (float*)d_out;

  hipMemsetAsync(out, 0, out_size, stream);   // graph-capturable memset node
  gmm_kernel<<<NBLK, NTHR, 0, stream>>>(x, wl, means, lv, out);
}